// Round 5
// baseline (349.999 us; speedup 1.0000x reference)
//
#include <hip/hip_runtime.h>
#include <stdint.h>

#define HW   4096
#define CIN  512

typedef __attribute__((ext_vector_type(8))) short short8;
typedef __attribute__((ext_vector_type(4))) float f32x4;
typedef unsigned short u16;

__device__ __forceinline__ u16 f2bf(float f) {
  union { float f; uint32_t u; } c; c.f = f;
  uint32_t r = (c.u + 0x7FFFu + ((c.u >> 16) & 1u)) >> 16;
  return (u16)r;
}
__device__ __forceinline__ float bf2f(u16 h) {
  union { uint32_t u; float f; } c; c.u = ((uint32_t)h) << 16;
  return c.f;
}

// ---------------------------------------------------------------------------
// x (B,C,HW) fp32  ->  xbT (B*HW, C) bf16   (64x64 tile transpose via LDS)
// ---------------------------------------------------------------------------
__global__ __launch_bounds__(256) void cast_xT(const float* __restrict__ x,
                                               u16* __restrict__ xbT) {
  __shared__ u16 t[64 * 72];
  int p0 = blockIdx.x * 64, c0 = blockIdx.y * 64, b = blockIdx.z;
  int tid = threadIdx.x, r = tid >> 2, ch = tid & 3;
  const float* xp = x + ((size_t)b * CIN + c0 + r) * HW + p0 + ch * 16;
  float4 f0 = *(const float4*)(xp + 0);
  float4 f1 = *(const float4*)(xp + 4);
  float4 f2 = *(const float4*)(xp + 8);
  float4 f3 = *(const float4*)(xp + 12);
  u16* tr = &t[r * 72 + ch * 16];
  tr[0] = f2bf(f0.x); tr[1] = f2bf(f0.y); tr[2] = f2bf(f0.z); tr[3] = f2bf(f0.w);
  tr[4] = f2bf(f1.x); tr[5] = f2bf(f1.y); tr[6] = f2bf(f1.z); tr[7] = f2bf(f1.w);
  tr[8] = f2bf(f2.x); tr[9] = f2bf(f2.y); tr[10] = f2bf(f2.z); tr[11] = f2bf(f2.w);
  tr[12] = f2bf(f3.x); tr[13] = f2bf(f3.y); tr[14] = f2bf(f3.z); tr[15] = f2bf(f3.w);
  __syncthreads();
  u16 o[16];
#pragma unroll
  for (int j = 0; j < 16; j++) o[j] = t[(ch * 16 + j) * 72 + r];
  u16* op = xbT + ((size_t)b * HW + p0 + r) * CIN + c0 + ch * 16;
  *(short8*)(op) = *(short8*)&o[0];
  *(short8*)(op + 8) = *(short8*)&o[8];
}

// ---------------------------------------------------------------------------
// weights -> bf16; wqk = [Wq*log2e; Wk] (128,512); bqk = [bq*log2e; bk]
// (log2e folded into q so attention can use raw exp2)
// ---------------------------------------------------------------------------
__global__ void cast_w(const float* __restrict__ Wq, const float* __restrict__ Wk,
                       const float* __restrict__ Wv, const float* __restrict__ Wd,
                       const float* __restrict__ bq, const float* __restrict__ bk,
                       u16* __restrict__ wqk, u16* __restrict__ wv,
                       u16* __restrict__ wd, float* __restrict__ bqk) {
  const float LOG2E = 1.4426950408889634f;
  int i = blockIdx.x * 256 + threadIdx.x;
  if (i < 65536) wqk[i] = f2bf(i < 32768 ? Wq[i] * LOG2E : Wk[i - 32768]);
  if (i < 262144) { wv[i] = f2bf(Wv[i]); wd[i] = f2bf(Wd[i]); }
  if (i < 128) bqk[i] = (i < 64) ? bq[i] * LOG2E : bk[i - 64];
}

// ---------------------------------------------------------------------------
// Generic GEMM: C(M,N) = A(M,K) * BT(N,K)^T  (both bf16, K-contiguous rows)
// 128x128 tile, BK=32, 256 thr / 4 waves, each wave 64x64 (4x4 mfma tiles).
// ---------------------------------------------------------------------------
__global__ __launch_bounds__(256) void gemm_bf16(
    const u16* __restrict__ A, const u16* __restrict__ BT,
    const float* __restrict__ bias, void* __restrict__ out,
    int M, int N, int K, int mode) {
  __shared__ u16 lds_a[128 * 40];
  __shared__ u16 lds_b[128 * 40];
  int tid = threadIdx.x;
  int w = tid >> 6, lane = tid & 63, m = lane & 15, g = lane >> 4;
  int wm = w >> 1, wn = w & 1;
  int m0 = blockIdx.y * 128, n0 = blockIdx.x * 128;
  int srow = tid >> 2, sch = tid & 3;
  const u16* pa = A + (size_t)(m0 + srow) * K + sch * 8;
  const u16* pb = BT + (size_t)(n0 + srow) * K + sch * 8;
  size_t rstep = (size_t)64 * K;

  f32x4 acc[4][4];
  f32x4 zero = {0.f, 0.f, 0.f, 0.f};
#pragma unroll
  for (int i = 0; i < 4; i++)
#pragma unroll
    for (int j = 0; j < 4; j++) acc[i][j] = zero;

  for (int k0 = 0; k0 < K; k0 += 32) {
    short8 av0 = *(const short8*)(pa + k0);
    short8 av1 = *(const short8*)(pa + rstep + k0);
    short8 bv0 = *(const short8*)(pb + k0);
    short8 bv1 = *(const short8*)(pb + rstep + k0);
    __syncthreads();
    *(short8*)&lds_a[srow * 40 + sch * 8] = av0;
    *(short8*)&lds_a[(srow + 64) * 40 + sch * 8] = av1;
    *(short8*)&lds_b[srow * 40 + sch * 8] = bv0;
    *(short8*)&lds_b[(srow + 64) * 40 + sch * 8] = bv1;
    __syncthreads();
    short8 af[4], bf[4];
#pragma unroll
    for (int i = 0; i < 4; i++)
      af[i] = *(const short8*)&lds_a[(wm * 64 + i * 16 + m) * 40 + g * 8];
#pragma unroll
    for (int j = 0; j < 4; j++)
      bf[j] = *(const short8*)&lds_b[(wn * 64 + j * 16 + m) * 40 + g * 8];
#pragma unroll
    for (int i = 0; i < 4; i++)
#pragma unroll
      for (int j = 0; j < 4; j++)
        acc[i][j] = __builtin_amdgcn_mfma_f32_16x16x32_bf16(af[i], bf[j], acc[i][j], 0, 0, 0);
  }

#pragma unroll
  for (int i = 0; i < 4; i++) {
#pragma unroll
    for (int j = 0; j < 4; j++) {
      int row_l = m0 + wm * 64 + i * 16 + g * 4;
      int col = n0 + wn * 64 + j * 16 + m;
#pragma unroll
      for (int r = 0; r < 4; r++) {
        int row = row_l + r;
        float v = acc[i][j][r];
        if (mode == 0) {
          v += bias[col];
          ((u16*)out)[(size_t)row * N + col] = f2bf(v);
        } else {
          v += bias[row];
          size_t addr = ((size_t)(col >> 12) * M + row) * HW + (col & (HW - 1));
          if (mode == 1) ((u16*)out)[addr] = f2bf(v);
          else           ((float*)out)[addr] = v;
        }
      }
    }
  }
}

// ---------------------------------------------------------------------------
// Fused attention + residual, single pass (no max subtraction; |S|<=~12).
// CHANNEL-SPLIT: 512 blocks = (b, 64-row i-tile, channel-half), 2 blocks/CU.
// Each block: full S-tile (QK + exp, duplicated across the chalf pair) but
// PV + epilogue for only 256 channels -> co-resident blocks hide each
// other's latency; barrier gates only own block's 8 waves.
// S-phase: wave (qg=w&3, jh=w>>2) -> 16 q x 64 j per 128-j tile.
// PV-phase: wave w -> channels chalf*256 + w*32.
// P via double-buffered LDS [64][128] u16, XOR-swizzled (row&15)<<3.
// V B-frags direct from global (L2-hot), issued early, consumed post-barrier.
// Q pre-scaled by log2e -> p = exp2(S).
// ---------------------------------------------------------------------------
__global__ __launch_bounds__(512, 4) void attn_fused(
    const u16* __restrict__ qkT, const u16* __restrict__ V,
    const u16* __restrict__ xbT, const float* __restrict__ gamma,
    u16* __restrict__ uT) {
  __shared__ u16 p_lds[2][64 * 128];
  __shared__ float red[2][64];
  __shared__ float sm_li[64];

  int tid = threadIdx.x;
  int w = tid >> 6, lane = tid & 63, m = lane & 15, g = lane >> 4;
  // XCD-contiguous swizzle: 64 consecutive work-ids per XCD; the (i0,chalf)
  // pair stays adjacent -> same XCD shares K/Q L2 lines.
  int wk = ((blockIdx.x & 7) << 6) + (blockIdx.x >> 3);
  int b = wk >> 7;
  int rem = wk & 127;
  int i0 = (rem >> 1) << 6;
  int chalf = rem & 1;
  int qg = w & 3, jh = w >> 2;
  size_t qbase = (size_t)b * HW + i0;

  // Q A-fragments: queries qg*16 + m, k = ks*32 + g*8 .. +8
  short8 aq[2];
#pragma unroll
  for (int ks = 0; ks < 2; ks++)
    aq[ks] = *(const short8*)(qkT + (qbase + qg * 16 + m) * 128 + ks * 32 + g * 8);

  f32x4 acc[4][2];
  f32x4 zero = {0.f, 0.f, 0.f, 0.f};
#pragma unroll
  for (int i = 0; i < 4; i++)
#pragma unroll
    for (int j = 0; j < 2; j++) acc[i][j] = zero;
  float lr[4] = {0.f, 0.f, 0.f, 0.f};

  int wch = (chalf << 8) + w * 32;
  const u16* vbase = V + (size_t)b * CIN * HW;
  const u16* kbase = qkT + (size_t)b * HW * 128 + 64;

  for (int t = 0; t < 32; t++) {
    int j0 = t * 128;
    // ---- issue V B-fragment loads early (consumed after the barrier) ----
    short8 vf[8];
#pragma unroll
    for (int ct = 0; ct < 2; ct++) {
      const u16* vr = vbase + (size_t)(wch + ct * 16 + m) * HW + j0 + g * 8;
#pragma unroll
      for (int ks = 0; ks < 4; ks++)
        vf[ct * 4 + ks] = *(const short8*)(vr + ks * 32);
    }
    // ---- S = QK^T for this wave's 16 q x 64 j; P = exp2(S) -> LDS ----
    u16* pb = p_lds[t & 1];
#pragma unroll
    for (int jtl = 0; jtl < 4; jtl++) {
      const u16* kr = kbase + (size_t)(j0 + jh * 64 + jtl * 16 + m) * 128;
      f32x4 s = zero;
#pragma unroll
      for (int ks = 0; ks < 2; ks++) {
        short8 bk = *(const short8*)(kr + ks * 32 + g * 8);
        s = __builtin_amdgcn_mfma_f32_16x16x32_bf16(aq[ks], bk, s, 0, 0, 0);
      }
      int col = jh * 64 + jtl * 16 + m;
#pragma unroll
      for (int r = 0; r < 4; r++) {
        float p = exp2f(s[r]);
        lr[r] += p;
        int row = qg * 16 + g * 4 + r;
        pb[row * 128 + (col ^ ((row & 15) << 3))] = f2bf(p);
      }
    }
    __syncthreads();
    // ---- PV: O += P * V' (A from LDS, B = vf regs) ----
    __builtin_amdgcn_s_setprio(1);
#pragma unroll
    for (int ks = 0; ks < 4; ks++) {
      short8 pa[4];
#pragma unroll
      for (int i2 = 0; i2 < 4; i2++)
        pa[i2] = *(const short8*)&pb[(i2 * 16 + m) * 128 + ((ks * 32 + g * 8) ^ (m << 3))];
#pragma unroll
      for (int i2 = 0; i2 < 4; i2++)
#pragma unroll
        for (int ct = 0; ct < 2; ct++)
          acc[i2][ct] = __builtin_amdgcn_mfma_f32_16x16x32_bf16(
              pa[i2], vf[ct * 4 + ks], acc[i2][ct], 0, 0, 0);
    }
    __builtin_amdgcn_s_setprio(0);
  }

  // ---- softmax denominator: reduce lr over 16 key-lanes, then jh pair ----
#pragma unroll
  for (int r = 0; r < 4; r++) {
#pragma unroll
    for (int off = 1; off < 16; off <<= 1)
      lr[r] += __shfl_xor(lr[r], off);
  }
  __syncthreads();
  if (m == 0) {
#pragma unroll
    for (int r = 0; r < 4; r++) red[jh][qg * 16 + g * 4 + r] = lr[r];
  }
  __syncthreads();
  if (tid < 64) sm_li[tid] = 1.0f / (red[0][tid] + red[1][tid]);
  __syncthreads();

  // ---- epilogue: uT = gamma * (acc * li) + x ----
  float gm = gamma[0];
#pragma unroll
  for (int i2 = 0; i2 < 4; i2++) {
#pragma unroll
    for (int ct = 0; ct < 2; ct++) {
#pragma unroll
      for (int r = 0; r < 4; r++) {
        int il = i2 * 16 + g * 4 + r;
        float o = acc[i2][ct][r] * sm_li[il];
        size_t row = qbase + il;
        int c = wch + ct * 16 + m;
        float xv = bf2f(xbT[row * CIN + c]);
        uT[row * CIN + c] = f2bf(gm * o + xv);
      }
    }
  }
}

// ---------------------------------------------------------------------------
extern "C" void kernel_launch(void* const* d_in, const int* in_sizes, int n_in,
                              void* d_out, int out_size, void* d_ws, size_t ws_size,
                              hipStream_t stream) {
  const float* x     = (const float*)d_in[0];
  const float* Wq    = (const float*)d_in[1];
  const float* bq    = (const float*)d_in[2];
  const float* Wk    = (const float*)d_in[3];
  const float* bk    = (const float*)d_in[4];
  const float* Wv    = (const float*)d_in[5];
  const float* bv    = (const float*)d_in[6];
  const float* gamma = (const float*)d_in[7];
  const float* Wd    = (const float*)d_in[8];
  const float* bd    = (const float*)d_in[9];

  char* ws = (char*)d_ws;
  size_t off = 0;
  auto alloc = [&](size_t bytes) {
    void* p = ws + off;
    off += (bytes + 255) & ~(size_t)255;
    return p;
  };
  u16*   xbT = (u16*)alloc((size_t)16384 * 512 * 2);
  u16*   qkT = (u16*)alloc((size_t)16384 * 128 * 2);
  u16*   vb  = (u16*)alloc((size_t)16384 * 512 * 2);
  u16*   uT  = (u16*)alloc((size_t)16384 * 512 * 2);
  u16*   wqk = (u16*)alloc((size_t)65536 * 2);
  u16*   wvb = (u16*)alloc((size_t)262144 * 2);
  u16*   wdb = (u16*)alloc((size_t)262144 * 2);
  float* bqk = (float*)alloc(128 * 4);
  if (off > ws_size) return;

  cast_xT<<<dim3(64, 8, 4), 256, 0, stream>>>(x, xbT);
  cast_w<<<1024, 256, 0, stream>>>(Wq, Wk, Wv, Wd, bq, bk, wqk, wvb, wdb, bqk);
  gemm_bf16<<<dim3(1, 128), 256, 0, stream>>>(xbT, wqk, bqk, qkT, 16384, 128, 512, 0);
  gemm_bf16<<<dim3(128, 4), 256, 0, stream>>>(wvb, xbT, bv, vb, 512, 16384, 512, 1);
  attn_fused<<<dim3(512), 512, 0, stream>>>(qkT, vb, xbT, gamma, uT);
  gemm_bf16<<<dim3(128, 4), 256, 0, stream>>>(wdb, uT, bd, d_out, 512, 16384, 512, 2);
}

// Round 6
// 266.796 us; speedup vs baseline: 1.3119x; 1.3119x over previous
//
#include <hip/hip_runtime.h>
#include <stdint.h>

#define HW   4096
#define CIN  512

typedef __attribute__((ext_vector_type(8))) short short8;
typedef __attribute__((ext_vector_type(4))) float f32x4;
typedef unsigned short u16;

__device__ __forceinline__ u16 f2bf(float f) {
  union { float f; uint32_t u; } c; c.f = f;
  uint32_t r = (c.u + 0x7FFFu + ((c.u >> 16) & 1u)) >> 16;
  return (u16)r;
}
__device__ __forceinline__ float bf2f(u16 h) {
  union { uint32_t u; float f; } c; c.u = ((uint32_t)h) << 16;
  return c.f;
}

// ---------------------------------------------------------------------------
// x (B,C,HW) fp32  ->  xbT (B*HW, C) bf16   (64x64 tile transpose via LDS)
// ---------------------------------------------------------------------------
__global__ __launch_bounds__(256) void cast_xT(const float* __restrict__ x,
                                               u16* __restrict__ xbT) {
  __shared__ u16 t[64 * 72];
  int p0 = blockIdx.x * 64, c0 = blockIdx.y * 64, b = blockIdx.z;
  int tid = threadIdx.x, r = tid >> 2, ch = tid & 3;
  const float* xp = x + ((size_t)b * CIN + c0 + r) * HW + p0 + ch * 16;
  float4 f0 = *(const float4*)(xp + 0);
  float4 f1 = *(const float4*)(xp + 4);
  float4 f2 = *(const float4*)(xp + 8);
  float4 f3 = *(const float4*)(xp + 12);
  u16* tr = &t[r * 72 + ch * 16];
  tr[0] = f2bf(f0.x); tr[1] = f2bf(f0.y); tr[2] = f2bf(f0.z); tr[3] = f2bf(f0.w);
  tr[4] = f2bf(f1.x); tr[5] = f2bf(f1.y); tr[6] = f2bf(f1.z); tr[7] = f2bf(f1.w);
  tr[8] = f2bf(f2.x); tr[9] = f2bf(f2.y); tr[10] = f2bf(f2.z); tr[11] = f2bf(f2.w);
  tr[12] = f2bf(f3.x); tr[13] = f2bf(f3.y); tr[14] = f2bf(f3.z); tr[15] = f2bf(f3.w);
  __syncthreads();
  u16 o[16];
#pragma unroll
  for (int j = 0; j < 16; j++) o[j] = t[(ch * 16 + j) * 72 + r];
  u16* op = xbT + ((size_t)b * HW + p0 + r) * CIN + c0 + ch * 16;
  *(short8*)(op) = *(short8*)&o[0];
  *(short8*)(op + 8) = *(short8*)&o[8];
}

// ---------------------------------------------------------------------------
// weights -> bf16; wqk = [Wq*log2e; Wk] (128,512); bqk = [bq*log2e; bk]
// ---------------------------------------------------------------------------
__global__ void cast_w(const float* __restrict__ Wq, const float* __restrict__ Wk,
                       const float* __restrict__ Wv, const float* __restrict__ Wd,
                       const float* __restrict__ bq, const float* __restrict__ bk,
                       u16* __restrict__ wqk, u16* __restrict__ wv,
                       u16* __restrict__ wd, float* __restrict__ bqk) {
  const float LOG2E = 1.4426950408889634f;
  int i = blockIdx.x * 256 + threadIdx.x;
  if (i < 65536) wqk[i] = f2bf(i < 32768 ? Wq[i] * LOG2E : Wk[i - 32768]);
  if (i < 262144) { wv[i] = f2bf(Wv[i]); wd[i] = f2bf(Wd[i]); }
  if (i < 128) bqk[i] = (i < 64) ? bq[i] * LOG2E : bk[i - 64];
}

// ---------------------------------------------------------------------------
// Generic GEMM: C(M,N) = A(M,K) * BT(N,K)^T  (both bf16, K-contiguous rows)
// 128x128 tile, BK=32, 256 thr / 4 waves, each wave 64x64 (4x4 mfma tiles).
// ---------------------------------------------------------------------------
__global__ __launch_bounds__(256) void gemm_bf16(
    const u16* __restrict__ A, const u16* __restrict__ BT,
    const float* __restrict__ bias, void* __restrict__ out,
    int M, int N, int K, int mode) {
  __shared__ u16 lds_a[128 * 40];
  __shared__ u16 lds_b[128 * 40];
  int tid = threadIdx.x;
  int w = tid >> 6, lane = tid & 63, m = lane & 15, g = lane >> 4;
  int wm = w >> 1, wn = w & 1;
  int m0 = blockIdx.y * 128, n0 = blockIdx.x * 128;
  int srow = tid >> 2, sch = tid & 3;
  const u16* pa = A + (size_t)(m0 + srow) * K + sch * 8;
  const u16* pb = BT + (size_t)(n0 + srow) * K + sch * 8;
  size_t rstep = (size_t)64 * K;

  f32x4 acc[4][4];
  f32x4 zero = {0.f, 0.f, 0.f, 0.f};
#pragma unroll
  for (int i = 0; i < 4; i++)
#pragma unroll
    for (int j = 0; j < 4; j++) acc[i][j] = zero;

  for (int k0 = 0; k0 < K; k0 += 32) {
    short8 av0 = *(const short8*)(pa + k0);
    short8 av1 = *(const short8*)(pa + rstep + k0);
    short8 bv0 = *(const short8*)(pb + k0);
    short8 bv1 = *(const short8*)(pb + rstep + k0);
    __syncthreads();
    *(short8*)&lds_a[srow * 40 + sch * 8] = av0;
    *(short8*)&lds_a[(srow + 64) * 40 + sch * 8] = av1;
    *(short8*)&lds_b[srow * 40 + sch * 8] = bv0;
    *(short8*)&lds_b[(srow + 64) * 40 + sch * 8] = bv1;
    __syncthreads();
    short8 af[4], bf[4];
#pragma unroll
    for (int i = 0; i < 4; i++)
      af[i] = *(const short8*)&lds_a[(wm * 64 + i * 16 + m) * 40 + g * 8];
#pragma unroll
    for (int j = 0; j < 4; j++)
      bf[j] = *(const short8*)&lds_b[(wn * 64 + j * 16 + m) * 40 + g * 8];
#pragma unroll
    for (int i = 0; i < 4; i++)
#pragma unroll
      for (int j = 0; j < 4; j++)
        acc[i][j] = __builtin_amdgcn_mfma_f32_16x16x32_bf16(af[i], bf[j], acc[i][j], 0, 0, 0);
  }

#pragma unroll
  for (int i = 0; i < 4; i++) {
#pragma unroll
    for (int j = 0; j < 4; j++) {
      int row_l = m0 + wm * 64 + i * 16 + g * 4;
      int col = n0 + wn * 64 + j * 16 + m;
#pragma unroll
      for (int r = 0; r < 4; r++) {
        int row = row_l + r;
        float v = acc[i][j][r];
        if (mode == 0) {
          v += bias[col];
          ((u16*)out)[(size_t)row * N + col] = f2bf(v);
        } else {
          v += bias[row];
          size_t addr = ((size_t)(col >> 12) * M + row) * HW + (col & (HW - 1));
          if (mode == 1) ((u16*)out)[addr] = f2bf(v);
          else           ((float*)out)[addr] = v;
        }
      }
    }
  }
}

// ---------------------------------------------------------------------------
// Fused attention + residual, single pass (no max subtraction; |S|<=~12).
// 64 q-rows per block, 256 blocks (1/CU), 16 waves (1024 thr, 4 waves/SIMD).
// Same total work/traffic as the 8-wave R4 version, but per-wave slices are
// halved -> double the wave-level parallelism to hide K/V L2 latency.
// S-phase: wave (qg=w&3, jq=w>>2) -> 16 q x 32 j per 128-j tile.
// PV-phase: wave w -> channels w*32..+32, all 64 q.
// P via double-buffered LDS [64][128] u16, XOR-swizzled (row&15)<<3.
// V B-frags direct from global (L2-hot), issued early, consumed post-barrier.
// Q pre-scaled by log2e -> p = exp2(S).
// ---------------------------------------------------------------------------
__global__ __launch_bounds__(1024, 4) void attn_fused(
    const u16* __restrict__ qkT, const u16* __restrict__ V,
    const u16* __restrict__ xbT, const float* __restrict__ gamma,
    u16* __restrict__ uT) {
  __shared__ u16 p_lds[2][64 * 128];
  __shared__ float red[4][64];
  __shared__ float sm_li[64];

  int tid = threadIdx.x;
  int w = tid >> 6, lane = tid & 63, m = lane & 15, g = lane >> 4;
  // XCD-contiguous swizzle: 256 blocks, 32 contiguous work-ids per XCD
  int wk = ((blockIdx.x & 7) << 5) + (blockIdx.x >> 3);
  int b = wk >> 6;
  int i0 = (wk & 63) << 6;
  int qg = w & 3, jq = w >> 2;
  size_t qbase = (size_t)b * HW + i0;

  // Q A-fragments: queries qg*16 + m, k = ks*32 + g*8 .. +8
  short8 aq[2];
#pragma unroll
  for (int ks = 0; ks < 2; ks++)
    aq[ks] = *(const short8*)(qkT + (qbase + qg * 16 + m) * 128 + ks * 32 + g * 8);

  f32x4 acc[4][2];
  f32x4 zero = {0.f, 0.f, 0.f, 0.f};
#pragma unroll
  for (int i = 0; i < 4; i++)
#pragma unroll
    for (int j = 0; j < 2; j++) acc[i][j] = zero;
  float lr[4] = {0.f, 0.f, 0.f, 0.f};

  int wch = w * 32;
  const u16* vbase = V + (size_t)b * CIN * HW;
  const u16* kbase = qkT + (size_t)b * HW * 128 + 64;

  for (int t = 0; t < 32; t++) {
    int j0 = t * 128;
    // ---- issue V B-fragment loads early (consumed after the barrier) ----
    short8 vf[8];
#pragma unroll
    for (int ct = 0; ct < 2; ct++) {
      const u16* vr = vbase + (size_t)(wch + ct * 16 + m) * HW + j0 + g * 8;
#pragma unroll
      for (int ks = 0; ks < 4; ks++)
        vf[ct * 4 + ks] = *(const short8*)(vr + ks * 32);
    }
    // ---- S = QK^T for this wave's 16 q x 32 j; P = exp2(S) -> LDS ----
    u16* pb = p_lds[t & 1];
#pragma unroll
    for (int jtl = 0; jtl < 2; jtl++) {
      const u16* kr = kbase + (size_t)(j0 + jq * 32 + jtl * 16 + m) * 128;
      f32x4 s = zero;
#pragma unroll
      for (int ks = 0; ks < 2; ks++) {
        short8 bk = *(const short8*)(kr + ks * 32 + g * 8);
        s = __builtin_amdgcn_mfma_f32_16x16x32_bf16(aq[ks], bk, s, 0, 0, 0);
      }
      int col = jq * 32 + jtl * 16 + m;
#pragma unroll
      for (int r = 0; r < 4; r++) {
        float p = exp2f(s[r]);
        lr[r] += p;
        int row = qg * 16 + g * 4 + r;
        pb[row * 128 + (col ^ ((row & 15) << 3))] = f2bf(p);
      }
    }
    __syncthreads();
    // ---- PV: O += P * V' (A from LDS, B = vf regs) ----
#pragma unroll
    for (int ks = 0; ks < 4; ks++) {
      short8 pa[4];
#pragma unroll
      for (int i2 = 0; i2 < 4; i2++)
        pa[i2] = *(const short8*)&pb[(i2 * 16 + m) * 128 + ((ks * 32 + g * 8) ^ (m << 3))];
#pragma unroll
      for (int i2 = 0; i2 < 4; i2++)
#pragma unroll
        for (int ct = 0; ct < 2; ct++)
          acc[i2][ct] = __builtin_amdgcn_mfma_f32_16x16x32_bf16(
              pa[i2], vf[ct * 4 + ks], acc[i2][ct], 0, 0, 0);
    }
  }

  // ---- softmax denominator: reduce lr over 16 key-lanes, then 4 jq ----
#pragma unroll
  for (int r = 0; r < 4; r++) {
#pragma unroll
    for (int off = 1; off < 16; off <<= 1)
      lr[r] += __shfl_xor(lr[r], off);
  }
  __syncthreads();
  if (m == 0) {
#pragma unroll
    for (int r = 0; r < 4; r++) red[jq][qg * 16 + g * 4 + r] = lr[r];
  }
  __syncthreads();
  if (tid < 64)
    sm_li[tid] = 1.0f / (red[0][tid] + red[1][tid] + red[2][tid] + red[3][tid]);
  __syncthreads();

  // ---- epilogue: uT = gamma * (acc * li) + x ----
  float gm = gamma[0];
#pragma unroll
  for (int i2 = 0; i2 < 4; i2++) {
#pragma unroll
    for (int ct = 0; ct < 2; ct++) {
#pragma unroll
      for (int r = 0; r < 4; r++) {
        int il = i2 * 16 + g * 4 + r;
        float o = acc[i2][ct][r] * sm_li[il];
        size_t row = qbase + il;
        int c = wch + ct * 16 + m;
        float xv = bf2f(xbT[row * CIN + c]);
        uT[row * CIN + c] = f2bf(gm * o + xv);
      }
    }
  }
}

// ---------------------------------------------------------------------------
extern "C" void kernel_launch(void* const* d_in, const int* in_sizes, int n_in,
                              void* d_out, int out_size, void* d_ws, size_t ws_size,
                              hipStream_t stream) {
  const float* x     = (const float*)d_in[0];
  const float* Wq    = (const float*)d_in[1];
  const float* bq    = (const float*)d_in[2];
  const float* Wk    = (const float*)d_in[3];
  const float* bk    = (const float*)d_in[4];
  const float* Wv    = (const float*)d_in[5];
  const float* bv    = (const float*)d_in[6];
  const float* gamma = (const float*)d_in[7];
  const float* Wd    = (const float*)d_in[8];
  const float* bd    = (const float*)d_in[9];

  char* ws = (char*)d_ws;
  size_t off = 0;
  auto alloc = [&](size_t bytes) {
    void* p = ws + off;
    off += (bytes + 255) & ~(size_t)255;
    return p;
  };
  u16*   xbT = (u16*)alloc((size_t)16384 * 512 * 2);
  u16*   qkT = (u16*)alloc((size_t)16384 * 128 * 2);
  u16*   vb  = (u16*)alloc((size_t)16384 * 512 * 2);
  u16*   uT  = (u16*)alloc((size_t)16384 * 512 * 2);
  u16*   wqk = (u16*)alloc((size_t)65536 * 2);
  u16*   wvb = (u16*)alloc((size_t)262144 * 2);
  u16*   wdb = (u16*)alloc((size_t)262144 * 2);
  float* bqk = (float*)alloc(128 * 4);
  if (off > ws_size) return;

  cast_xT<<<dim3(64, 8, 4), 256, 0, stream>>>(x, xbT);
  cast_w<<<1024, 256, 0, stream>>>(Wq, Wk, Wv, Wd, bq, bk, wqk, wvb, wdb, bqk);
  gemm_bf16<<<dim3(1, 128), 256, 0, stream>>>(xbT, wqk, bqk, qkT, 16384, 128, 512, 0);
  gemm_bf16<<<dim3(128, 4), 256, 0, stream>>>(wvb, xbT, bv, vb, 512, 16384, 512, 1);
  attn_fused<<<dim3(256), 1024, 0, stream>>>(qkT, vb, xbT, gamma, uT);
  gemm_bf16<<<dim3(128, 4), 256, 0, stream>>>(wdb, uT, bd, d_out, 512, 16384, 512, 2);
}

// Round 7
// 246.559 us; speedup vs baseline: 1.4195x; 1.0821x over previous
//
#include <hip/hip_runtime.h>
#include <stdint.h>

#define HW   4096
#define CIN  512

typedef __attribute__((ext_vector_type(8))) short short8;
typedef __attribute__((ext_vector_type(4))) float f32x4;
typedef unsigned short u16;

#define GL16(src, ldsdst) __builtin_amdgcn_global_load_lds(                    \
    (const __attribute__((address_space(1))) void*)(src),                      \
    (__attribute__((address_space(3))) void*)(ldsdst), 16, 0, 0)

__device__ __forceinline__ u16 f2bf(float f) {
  union { float f; uint32_t u; } c; c.f = f;
  uint32_t r = (c.u + 0x7FFFu + ((c.u >> 16) & 1u)) >> 16;
  return (u16)r;
}
__device__ __forceinline__ float bf2f(u16 h) {
  union { uint32_t u; float f; } c; c.u = ((uint32_t)h) << 16;
  return c.f;
}

// ---------------------------------------------------------------------------
// x (B,C,HW) fp32  ->  xbT (B*HW, C) bf16   (64x64 tile transpose via LDS)
// ---------------------------------------------------------------------------
__global__ __launch_bounds__(256) void cast_xT(const float* __restrict__ x,
                                               u16* __restrict__ xbT) {
  __shared__ u16 t[64 * 72];
  int p0 = blockIdx.x * 64, c0 = blockIdx.y * 64, b = blockIdx.z;
  int tid = threadIdx.x, r = tid >> 2, ch = tid & 3;
  const float* xp = x + ((size_t)b * CIN + c0 + r) * HW + p0 + ch * 16;
  float4 f0 = *(const float4*)(xp + 0);
  float4 f1 = *(const float4*)(xp + 4);
  float4 f2 = *(const float4*)(xp + 8);
  float4 f3 = *(const float4*)(xp + 12);
  u16* tr = &t[r * 72 + ch * 16];
  tr[0] = f2bf(f0.x); tr[1] = f2bf(f0.y); tr[2] = f2bf(f0.z); tr[3] = f2bf(f0.w);
  tr[4] = f2bf(f1.x); tr[5] = f2bf(f1.y); tr[6] = f2bf(f1.z); tr[7] = f2bf(f1.w);
  tr[8] = f2bf(f2.x); tr[9] = f2bf(f2.y); tr[10] = f2bf(f2.z); tr[11] = f2bf(f2.w);
  tr[12] = f2bf(f3.x); tr[13] = f2bf(f3.y); tr[14] = f2bf(f3.z); tr[15] = f2bf(f3.w);
  __syncthreads();
  u16 o[16];
#pragma unroll
  for (int j = 0; j < 16; j++) o[j] = t[(ch * 16 + j) * 72 + r];
  u16* op = xbT + ((size_t)b * HW + p0 + r) * CIN + c0 + ch * 16;
  *(short8*)(op) = *(short8*)&o[0];
  *(short8*)(op + 8) = *(short8*)&o[8];
}

// ---------------------------------------------------------------------------
// weights -> bf16; wqk = [Wq*log2e; Wk] (128,512); bqk = [bq*log2e; bk]
// ---------------------------------------------------------------------------
__global__ void cast_w(const float* __restrict__ Wq, const float* __restrict__ Wk,
                       const float* __restrict__ Wv, const float* __restrict__ Wd,
                       const float* __restrict__ bq, const float* __restrict__ bk,
                       u16* __restrict__ wqk, u16* __restrict__ wv,
                       u16* __restrict__ wd, float* __restrict__ bqk) {
  const float LOG2E = 1.4426950408889634f;
  int i = blockIdx.x * 256 + threadIdx.x;
  if (i < 65536) wqk[i] = f2bf(i < 32768 ? Wq[i] * LOG2E : Wk[i - 32768]);
  if (i < 262144) { wv[i] = f2bf(Wv[i]); wd[i] = f2bf(Wd[i]); }
  if (i < 128) bqk[i] = (i < 64) ? bq[i] * LOG2E : bk[i - 64];
}

// ---------------------------------------------------------------------------
// Generic GEMM: C(M,N) = A(M,K) * BT(N,K)^T  (both bf16, K-contiguous rows)
// m97-style: 128x128 tile, BK=32, global_load_lds(16B) staging into linear
// [128][32] LDS, 2 barriers per K-step, 4 waves x (64x64 = 4x4 mfma) each.
// mode 0: out row-major (M,N) bf16, bias[col]
// mode 1: out (B, M, HW) bf16, col=b*HW+p, bias[row]
// mode 2: out (B, M, HW) fp32, bias[row]
// ---------------------------------------------------------------------------
__global__ __launch_bounds__(256) void gemm_bf16(
    const u16* __restrict__ A, const u16* __restrict__ BT,
    const float* __restrict__ bias, void* __restrict__ out,
    int M, int N, int K, int mode) {
  __shared__ u16 la[128 * 32];
  __shared__ u16 lb[128 * 32];
  int tid = threadIdx.x;
  int w = tid >> 6, lane = tid & 63, m = lane & 15, g = lane >> 4;
  int wm = w >> 1, wn = w & 1;
  int m0 = blockIdx.y * 128, n0 = blockIdx.x * 128;
  int sr = lane >> 2, sc = (lane & 3) * 8;   // 16 rows x 32k per wave-instr
  const u16* pa0 = A + (size_t)(m0 + w * 32 + sr) * K + sc;
  const u16* pa1 = pa0 + (size_t)16 * K;
  const u16* pb0 = BT + (size_t)(n0 + w * 32 + sr) * K + sc;
  const u16* pb1 = pb0 + (size_t)16 * K;
  u16* la0 = &la[(w * 32) * 32];
  u16* la1 = &la[(w * 32 + 16) * 32];
  u16* lb0 = &lb[(w * 32) * 32];
  u16* lb1 = &lb[(w * 32 + 16) * 32];

  f32x4 acc[4][4];
  f32x4 zero = {0.f, 0.f, 0.f, 0.f};
#pragma unroll
  for (int i = 0; i < 4; i++)
#pragma unroll
    for (int j = 0; j < 4; j++) acc[i][j] = zero;

  for (int k0 = 0; k0 < K; k0 += 32) {
    __syncthreads();
    GL16(pa0 + k0, la0);
    GL16(pa1 + k0, la1);
    GL16(pb0 + k0, lb0);
    GL16(pb1 + k0, lb1);
    __syncthreads();
    short8 af[4], bf[4];
#pragma unroll
    for (int i = 0; i < 4; i++)
      af[i] = *(const short8*)&la[(wm * 64 + i * 16 + m) * 32 + g * 8];
#pragma unroll
    for (int j = 0; j < 4; j++)
      bf[j] = *(const short8*)&lb[(wn * 64 + j * 16 + m) * 32 + g * 8];
#pragma unroll
    for (int i = 0; i < 4; i++)
#pragma unroll
      for (int j = 0; j < 4; j++)
        acc[i][j] = __builtin_amdgcn_mfma_f32_16x16x32_bf16(af[i], bf[j], acc[i][j], 0, 0, 0);
  }

#pragma unroll
  for (int i = 0; i < 4; i++) {
#pragma unroll
    for (int j = 0; j < 4; j++) {
      int row_l = m0 + wm * 64 + i * 16 + g * 4;
      int col = n0 + wn * 64 + j * 16 + m;
#pragma unroll
      for (int r = 0; r < 4; r++) {
        int row = row_l + r;
        float v = acc[i][j][r];
        if (mode == 0) {
          v += bias[col];
          ((u16*)out)[(size_t)row * N + col] = f2bf(v);
        } else {
          v += bias[row];
          size_t addr = ((size_t)(col >> 12) * M + row) * HW + (col & (HW - 1));
          if (mode == 1) ((u16*)out)[addr] = f2bf(v);
          else           ((float*)out)[addr] = v;
        }
      }
    }
  }
}

// ---------------------------------------------------------------------------
// ppass: P = exp2(Q K^T) materialized bf16 + exact row-sum reciprocals.
// Grid: nb*64 blocks, 64 q-rows each, 512 thr (8 waves).
// Wave (qg=w&3, jh=w>>2): 16 q-rows x 2048 j (jh half).
// K panel (256 j x 64 k) staged in LDS, XOR-swizzled seg^=(row&7).
// qkT: (B*HW,128) cols 0..63 q (pre-scaled log2e), 64..127 k.
// P: (nb*HW, HW) bf16 (local batch index); li: (B*HW) fp32 = 1/rowsum.
// No max subtraction: |S| bounded ~17 after log2e fold -> exp2 safe.
// ---------------------------------------------------------------------------
__global__ __launch_bounds__(512) void ppass(
    const u16* __restrict__ qkT, u16* __restrict__ P,
    float* __restrict__ li, int b0) {
  __shared__ u16 kl[256 * 64];
  __shared__ float red[2][64];
  int tid = threadIdx.x;
  int w = tid >> 6, lane = tid & 63, m = lane & 15, g = lane >> 4;
  int blk = blockIdx.x;
  int bb = blk >> 6, b = b0 + bb;
  int q0 = (blk & 63) << 6;
  int qg = w & 3, jh = w >> 2;
  size_t qrow = (size_t)b * HW + q0;

  short8 aq[2];
#pragma unroll
  for (int ks = 0; ks < 2; ks++)
    aq[ks] = *(const short8*)(qkT + (qrow + qg * 16 + m) * 128 + ks * 32 + g * 8);

  float lr[4] = {0.f, 0.f, 0.f, 0.f};
  u16* Pb = P + ((size_t)bb * HW + q0) * HW;
  const u16* kb = qkT + (size_t)b * HW * 128 + 64;
  f32x4 zero = {0.f, 0.f, 0.f, 0.f};

  for (int jp = 0; jp < 16; jp++) {
    int j0 = jp * 256;
    __syncthreads();
    // stage K rows [j0, j0+256) x 64k, swizzled
#pragma unroll
    for (int it = 0; it < 4; it++) {
      int c = tid + it * 512;
      int row = c >> 3, seg = c & 7;
      short8 v = *(const short8*)(kb + (size_t)(j0 + row) * 128 + seg * 8);
      *(short8*)&kl[row * 64 + ((seg ^ (row & 7)) * 8)] = v;
    }
    __syncthreads();
#pragma unroll
    for (int jt = 0; jt < 8; jt++) {
      int jr = jh * 128 + jt * 16;
      int krow = jr + m;
      f32x4 s = zero;
#pragma unroll
      for (int ks = 0; ks < 2; ks++) {
        short8 bk = *(const short8*)&kl[krow * 64 + (((ks * 4 + g) ^ (krow & 7)) * 8)];
        s = __builtin_amdgcn_mfma_f32_16x16x32_bf16(aq[ks], bk, s, 0, 0, 0);
      }
      int j = j0 + jr + m;
#pragma unroll
      for (int r = 0; r < 4; r++) {
        float p = exp2f(s[r]);
        lr[r] += p;
        int q = qg * 16 + g * 4 + r;
        Pb[(size_t)q * HW + j] = f2bf(p);
      }
    }
  }
  // exact row sums: reduce over 16 key-lanes, then across jh halves
#pragma unroll
  for (int r = 0; r < 4; r++) {
#pragma unroll
    for (int off = 1; off < 16; off <<= 1)
      lr[r] += __shfl_xor(lr[r], off);
  }
  __syncthreads();
  if (m == 0) {
#pragma unroll
    for (int r = 0; r < 4; r++) red[jh][qg * 16 + g * 4 + r] = lr[r];
  }
  __syncthreads();
  if (tid < 64) li[qrow + tid] = 1.0f / (red[0][tid] + red[1][tid]);
}

// ---------------------------------------------------------------------------
// gemm_pv: uT = gamma * (P * V^T) .* li + xbT   (the PV contraction as a
// m97-style GEMM).  M=4096 q (per batch), N=512 c, K=4096 j.
// A = P (local-batch rows, K-contig), BT = V (B,512,HW) rows c, K-contig.
// Grid (4, 32, nb), 256 thr.
// ---------------------------------------------------------------------------
__global__ __launch_bounds__(256) void gemm_pv(
    const u16* __restrict__ P, const u16* __restrict__ V,
    const float* __restrict__ li, const u16* __restrict__ xbT,
    const float* __restrict__ gamma, u16* __restrict__ uT, int b0) {
  __shared__ u16 la[128 * 32];
  __shared__ u16 lb[128 * 32];
  int tid = threadIdx.x;
  int w = tid >> 6, lane = tid & 63, m = lane & 15, g = lane >> 4;
  int wm = w >> 1, wn = w & 1;
  int bb = blockIdx.z, b = b0 + bb;
  int n0 = blockIdx.x * 128;   // channel
  int m0 = blockIdx.y * 128;   // q row within batch
  const u16* A  = P + ((size_t)bb * HW + m0) * HW;
  const u16* BT = V + ((size_t)b * CIN + n0) * HW;
  int sr = lane >> 2, sc = (lane & 3) * 8;
  const u16* pa0 = A + (size_t)(w * 32 + sr) * HW + sc;
  const u16* pa1 = pa0 + (size_t)16 * HW;
  const u16* pb0 = BT + (size_t)(w * 32 + sr) * HW + sc;
  const u16* pb1 = pb0 + (size_t)16 * HW;
  u16* la0 = &la[(w * 32) * 32];
  u16* la1 = &la[(w * 32 + 16) * 32];
  u16* lb0 = &lb[(w * 32) * 32];
  u16* lb1 = &lb[(w * 32 + 16) * 32];

  f32x4 acc[4][4];
  f32x4 zero = {0.f, 0.f, 0.f, 0.f};
#pragma unroll
  for (int i = 0; i < 4; i++)
#pragma unroll
    for (int j = 0; j < 4; j++) acc[i][j] = zero;

  for (int k0 = 0; k0 < HW; k0 += 32) {
    __syncthreads();
    GL16(pa0 + k0, la0);
    GL16(pa1 + k0, la1);
    GL16(pb0 + k0, lb0);
    GL16(pb1 + k0, lb1);
    __syncthreads();
    short8 af[4], bf[4];
#pragma unroll
    for (int i = 0; i < 4; i++)
      af[i] = *(const short8*)&la[(wm * 64 + i * 16 + m) * 32 + g * 8];
#pragma unroll
    for (int j = 0; j < 4; j++)
      bf[j] = *(const short8*)&lb[(wn * 64 + j * 16 + m) * 32 + g * 8];
#pragma unroll
    for (int i = 0; i < 4; i++)
#pragma unroll
      for (int j = 0; j < 4; j++)
        acc[i][j] = __builtin_amdgcn_mfma_f32_16x16x32_bf16(af[i], bf[j], acc[i][j], 0, 0, 0);
  }

  float gm = gamma[0];
#pragma unroll
  for (int i = 0; i < 4; i++) {
#pragma unroll
    for (int j = 0; j < 4; j++) {
#pragma unroll
      for (int r = 0; r < 4; r++) {
        int q = m0 + wm * 64 + i * 16 + g * 4 + r;
        int c = n0 + wn * 64 + j * 16 + m;
        size_t row = (size_t)b * HW + q;
        float o = acc[i][j][r] * li[row];
        float xv = bf2f(xbT[row * CIN + c]);
        uT[row * CIN + c] = f2bf(gm * o + xv);
      }
    }
  }
}

// ---------------------------------------------------------------------------
extern "C" void kernel_launch(void* const* d_in, const int* in_sizes, int n_in,
                              void* d_out, int out_size, void* d_ws, size_t ws_size,
                              hipStream_t stream) {
  const float* x     = (const float*)d_in[0];
  const float* Wq    = (const float*)d_in[1];
  const float* bq    = (const float*)d_in[2];
  const float* Wk    = (const float*)d_in[3];
  const float* bk    = (const float*)d_in[4];
  const float* Wv    = (const float*)d_in[5];
  const float* bv    = (const float*)d_in[6];
  const float* gamma = (const float*)d_in[7];
  const float* Wd    = (const float*)d_in[8];
  const float* bd    = (const float*)d_in[9];

  char* ws = (char*)d_ws;
  size_t off = 0;
  auto alloc = [&](size_t bytes) {
    void* p = ws + off;
    off += (bytes + 255) & ~(size_t)255;
    return p;
  };
  u16*   xbT = (u16*)alloc((size_t)16384 * 512 * 2);
  u16*   qkT = (u16*)alloc((size_t)16384 * 128 * 2);
  u16*   vb  = (u16*)alloc((size_t)16384 * 512 * 2);
  u16*   uT  = (u16*)alloc((size_t)16384 * 512 * 2);
  u16*   wqk = (u16*)alloc((size_t)65536 * 2);
  u16*   wvb = (u16*)alloc((size_t)262144 * 2);
  u16*   wdb = (u16*)alloc((size_t)262144 * 2);
  float* bqk = (float*)alloc(128 * 4);
  float* li  = (float*)alloc((size_t)16384 * 4);
  // P buffer: 32 MB per staged batch; pick the largest staging that fits
  size_t PB = (size_t)HW * HW * 2;
  int nb = 0;
  if      (off + 4 * PB <= ws_size) nb = 4;
  else if (off + 2 * PB <= ws_size) nb = 2;
  else if (off + 1 * PB <= ws_size) nb = 1;
  if (nb == 0) return;  // workspace too small -> poison stays -> loud failure
  u16* Pbuf = (u16*)alloc(nb * PB);

  cast_xT<<<dim3(64, 8, 4), 256, 0, stream>>>(x, xbT);
  cast_w<<<1024, 256, 0, stream>>>(Wq, Wk, Wv, Wd, bq, bk, wqk, wvb, wdb, bqk);
  // qkT (16384,128) = xbT * wqk^T
  gemm_bf16<<<dim3(1, 128), 256, 0, stream>>>(xbT, wqk, bqk, qkT, 16384, 128, 512, 0);
  // v (B,512,HW) = Wv * x
  gemm_bf16<<<dim3(128, 4), 256, 0, stream>>>(wvb, xbT, bv, vb, 512, 16384, 512, 1);
  // attention: P materialize + PV GEMM (staged by batch groups of nb)
  for (int b0 = 0; b0 < 4; b0 += nb) {
    ppass<<<dim3(nb * 64), 512, 0, stream>>>(qkT, Pbuf, li, b0);
    gemm_pv<<<dim3(4, 32, nb), 256, 0, stream>>>(Pbuf, vb, li, xbT, gamma, uT, b0);
  }
  // pam_out (B,512,HW) fp32 = Wd * u
  gemm_bf16<<<dim3(128, 4), 256, 0, stream>>>(wdb, uT, bd, d_out, 512, 16384, 512, 2);
}